// Round 8
// baseline (192.092 us; speedup 1.0000x reference)
//
#include <hip/hip_runtime.h>
#include <stdint.h>

#define NB    1024   // batch
#define NUM   512    // nodes
#define HD    64     // hidden dim
#define NE    4096   // edges
#define MAIN  10     // softmax segment
#define HBS   72     // HB row stride (shorts): 144 B, 16B-aligned b128 slots

typedef __attribute__((ext_vector_type(8))) short short8;
typedef __attribute__((ext_vector_type(4))) float f32x4;

__device__ __forceinline__ short f2bf(float f) {
    uint32_t u = __float_as_uint(f);
    u += 0x7fffu + ((u >> 16) & 1u);   // RNE
    return (short)(u >> 16);
}
__device__ __forceinline__ float bf2f(short s) {
    return __uint_as_float(((uint32_t)(uint16_t)s) << 16);
}

// ---------------------------------------------------------------------------
// Single fused kernel: one block (1024 thr, 16 waves) per batch element.
// Each block redundantly builds the degree-sorted CSR (wave-shfl scans, LDS
// atomics) and computes B1 = (x .* emb) @ W1 via MFMA — removing the serial
// prep launch entirely. Then: SpMM1 -> MFMA(h1@W2) -> SpMM2(+fused W3
// epilogue) -> SpMM3 -> softmax/sigmoid.
// ---------------------------------------------------------------------------
__global__ __launch_bounds__(1024, 4) void gcn_one(
    const float* __restrict__ x, const float* __restrict__ emb,
    const float* __restrict__ W1, const float* __restrict__ W2,
    const float* __restrict__ b1, const float* __restrict__ b2,
    const float* __restrict__ W3, const float* __restrict__ b3,
    const int* __restrict__ erow, const int* __restrict__ ecol,
    float* __restrict__ out)
{
    __shared__ short HA[NUM * HD];     // 65536 B [node][64] (B1, later g = h1@W2)
    __shared__ short HB[NUM * HBS];    // 73728 B [node][72] (h1); overlays: CSR scratch, tv, slog
    __shared__ int   eps[NE];          // 16384 B packed edges (row<<16 | bf16 norm)
    __shared__ int   sptr[513];        // rank-CSR
    __shared__ int   scm[NUM];         // rank -> original column
    __shared__ int   wsum[16];
    __shared__ float sred[2];

    // CSR scratch overlaid on HB (dead before SpMM1 writes HB)
    int*   sdeg = (int*)HB;            // 512: degree, then bin cursors
    int*   aux  = sdeg + NUM;          // 512: histogram/scan, then edge cursors
    float* sdv  = (float*)(aux + NUM); // 512: dinv
    int*   rnk  = (int*)(sdv + NUM);   // 512: col -> rank
    int*   rdg  = rnk + NUM;           // 512: degree by rank
    // post-MFMA overlays on HB
    float* tv   = (float*)HB;          // 512 floats
    float* slog = ((float*)HB) + NUM;  // 512 floats

    const int t     = threadIdx.x;
    const int b     = blockIdx.x;
    const int lane  = t & 63;
    const int wave  = t >> 6;          // 0..15
    const int q     = lane >> 4;
    const int l15   = lane & 15;
    const int grp   = lane >> 3;       // column slot within wave
    const int dbase = (lane & 7) * 8;  // this lane's 8-dim strip

    // ================= in-block CSR build (degree-sorted ranks) =============
    if (t < NUM) { sdeg[t] = 0; aux[t] = 0; }
    __syncthreads();
    for (int e = t; e < NE; e += 1024) atomicAdd(&sdeg[ecol[e]], 1);
    __syncthreads();
    int deg = 0, dbin = 0;
    if (t < NUM) {
        deg  = sdeg[t];
        dbin = deg < NUM ? deg : NUM - 1;
        sdv[t] = deg > 0 ? rsqrtf((float)deg) : 0.0f;
        atomicAdd(&aux[dbin], 1);
    }
    __syncthreads();
    // inclusive scan of histogram aux[0..511] (waves 0..7, shfl-based)
    {
        int v = (t < NUM) ? aux[t] : 0;
        if (t < NUM) {
            #pragma unroll
            for (int ofs = 1; ofs < 64; ofs <<= 1) {
                int sh = __shfl_up(v, ofs, 64);
                if (lane >= ofs) v += sh;
            }
            if (lane == 63) wsum[wave] = v;
        }
        __syncthreads();
        if (t == 0) {
            int s = 0;
            #pragma unroll
            for (int w = 0; w < 8; ++w) { int tmp = wsum[w]; wsum[w] = s; s += tmp; }
        }
        __syncthreads();
        if (t < NUM) aux[t] = v + wsum[wave];
        __syncthreads();
    }
    if (t < NUM) sdeg[t] = (t == 0) ? 0 : aux[t - 1];   // sdeg := bin cursors
    __syncthreads();
    if (t < NUM) {
        int r = atomicAdd(&sdeg[dbin], 1);              // rank (degree-sorted)
        rnk[t] = r;
        rdg[r] = deg;
        scm[r] = t;
    }
    __syncthreads();
    // inclusive scan of rank-ordered degrees -> rank CSR
    {
        int dv = (t < NUM) ? rdg[t] : 0;
        int v  = dv;
        if (t < NUM) {
            #pragma unroll
            for (int ofs = 1; ofs < 64; ofs <<= 1) {
                int sh = __shfl_up(v, ofs, 64);
                if (lane >= ofs) v += sh;
            }
            if (lane == 63) wsum[wave] = v;
        }
        __syncthreads();
        if (t == 0) {
            int s = 0;
            #pragma unroll
            for (int w = 0; w < 8; ++w) { int tmp = wsum[w]; wsum[w] = s; s += tmp; }
        }
        __syncthreads();
        if (t < NUM) {
            int inc = v + wsum[wave];
            sptr[t] = inc - dv;
            if (t == NUM - 1) sptr[NUM] = inc;
        }
        __syncthreads();
    }
    if (t < NUM) aux[t] = sptr[rnk[t]];                 // aux := edge cursors (orig col)
    __syncthreads();
    for (int e = t; e < NE; e += 1024) {
        int c = ecol[e], rr = erow[e];
        int p = atomicAdd(&aux[c], 1);
        unsigned nb = (unsigned short)f2bf(sdv[rr] * sdv[c]);
        eps[p] = (rr << 16) | (int)nb;
    }
    __syncthreads();

    // ================= B1 = (x .* emb) @ W1 -> HA via MFMA ==================
    {
        short8 bfr[2][4];
        #pragma unroll
        for (int ks = 0; ks < 2; ++ks)
            #pragma unroll
            for (int nt = 0; nt < 4; ++nt) {
                short8 v;
                #pragma unroll
                for (int j = 0; j < 8; ++j)
                    v[j] = f2bf(W1[(ks * 32 + q * 8 + j) * HD + nt * 16 + l15]);
                bfr[ks][nt] = v;
            }
        f32x4 acc[2][4];
        #pragma unroll
        for (int mt = 0; mt < 2; ++mt)
            #pragma unroll
            for (int nt = 0; nt < 4; ++nt) acc[mt][nt] = (f32x4){0.f, 0.f, 0.f, 0.f};
        const int mbase = wave * 32;
        #pragma unroll
        for (int mt = 0; mt < 2; ++mt) {
            int r = mbase + mt * 16 + l15;
            float xr = x[b * NUM + r];
            #pragma unroll
            for (int ks = 0; ks < 2; ++ks) {
                const float* ep = &emb[r * HD + ks * 32 + q * 8];
                f32x4 e0 = *(const f32x4*)ep;
                f32x4 e1 = *(const f32x4*)(ep + 4);
                short8 af;
                af[0] = f2bf(xr * e0[0]); af[1] = f2bf(xr * e0[1]);
                af[2] = f2bf(xr * e0[2]); af[3] = f2bf(xr * e0[3]);
                af[4] = f2bf(xr * e1[0]); af[5] = f2bf(xr * e1[1]);
                af[6] = f2bf(xr * e1[2]); af[7] = f2bf(xr * e1[3]);
                #pragma unroll
                for (int nt = 0; nt < 4; ++nt)
                    acc[mt][nt] = __builtin_amdgcn_mfma_f32_16x16x32_bf16(
                        af, bfr[ks][nt], acc[mt][nt], 0, 0, 0);
            }
        }
        #pragma unroll
        for (int mt = 0; mt < 2; ++mt)
            #pragma unroll
            for (int nt = 0; nt < 4; ++nt)
                #pragma unroll
                for (int i = 0; i < 4; ++i)
                    HA[(mbase + mt * 16 + q * 4 + i) * HD + nt * 16 + l15] =
                        f2bf(acc[mt][nt][i]);
    }

    // per-lane bias/weight strips
    float b1v[8], b2v[8], w3v[8];
    {
        f32x4 u0 = *(const f32x4*)&b1[dbase], u1 = *(const f32x4*)&b1[dbase + 4];
        f32x4 v0 = *(const f32x4*)&b2[dbase], v1 = *(const f32x4*)&b2[dbase + 4];
        f32x4 w0 = *(const f32x4*)&W3[dbase], w1 = *(const f32x4*)&W3[dbase + 4];
        #pragma unroll
        for (int j = 0; j < 4; ++j) {
            b1v[j] = u0[j]; b1v[j + 4] = u1[j];
            b2v[j] = v0[j]; b2v[j + 4] = v1[j];
            w3v[j] = w0[j]; w3v[j + 4] = w1[j];
        }
    }
    __syncthreads();

#define EDGE_MAC(pe)                                                          \
    {                                                                         \
        float n = __uint_as_float((unsigned)(pe) << 16);                      \
        uint4 hv = *(const uint4*)&HA[((unsigned)(pe) >> 16) * HD + dbase];   \
        a[0] = fmaf(n, __uint_as_float(hv.x << 16), a[0]);                    \
        a[1] = fmaf(n, __uint_as_float(hv.x & 0xffff0000u), a[1]);            \
        a[2] = fmaf(n, __uint_as_float(hv.y << 16), a[2]);                    \
        a[3] = fmaf(n, __uint_as_float(hv.y & 0xffff0000u), a[3]);            \
        a[4] = fmaf(n, __uint_as_float(hv.z << 16), a[4]);                    \
        a[5] = fmaf(n, __uint_as_float(hv.z & 0xffff0000u), a[5]);            \
        a[6] = fmaf(n, __uint_as_float(hv.w << 16), a[6]);                    \
        a[7] = fmaf(n, __uint_as_float(hv.w & 0xffff0000u), a[7]);            \
    }

    // ---- SpMM1: h1 = relu(S @ B1 + b1) -> HB[c][d]
    #pragma unroll 1
    for (int set = 0; set < 4; ++set) {
        int r  = set * 128 + wave * 8 + grp;
        int e0 = sptr[r], e1 = sptr[r + 1];
        int c  = scm[r];
        float a[8];
        #pragma unroll
        for (int j = 0; j < 8; ++j) a[j] = 0.0f;
        int e = e0;
        for (; e + 2 <= e1; e += 2) {
            int pe0 = eps[e], pe1 = eps[e + 1];
            EDGE_MAC(pe0);
            EDGE_MAC(pe1);
        }
        if (e < e1) { int pe0 = eps[e]; EDGE_MAC(pe0); }
        short8 o;
        #pragma unroll
        for (int j = 0; j < 8; ++j) o[j] = f2bf(fmaxf(a[j] + b1v[j], 0.0f));
        *(short8*)&HB[c * HBS + dbase] = o;
    }
    __syncthreads();

    // ---- MFMA: g = h1 @ W2 -> HA[node][dout]
    {
        short8 bfr[2][4];
        #pragma unroll
        for (int ks = 0; ks < 2; ++ks)
            #pragma unroll
            for (int nt = 0; nt < 4; ++nt) {
                short8 v;
                #pragma unroll
                for (int j = 0; j < 8; ++j)
                    v[j] = f2bf(W2[(ks * 32 + q * 8 + j) * HD + nt * 16 + l15]);
                bfr[ks][nt] = v;
            }
        f32x4 acc[2][4];
        #pragma unroll
        for (int mt = 0; mt < 2; ++mt)
            #pragma unroll
            for (int nt = 0; nt < 4; ++nt) acc[mt][nt] = (f32x4){0.f, 0.f, 0.f, 0.f};
        const int mbase = wave * 32;
        #pragma unroll
        for (int mt = 0; mt < 2; ++mt)
            #pragma unroll
            for (int ks = 0; ks < 2; ++ks) {
                short8 af = *(const short8*)&HB[(mbase + mt * 16 + l15) * HBS
                                                + ks * 32 + q * 8];
                #pragma unroll
                for (int nt = 0; nt < 4; ++nt)
                    acc[mt][nt] = __builtin_amdgcn_mfma_f32_16x16x32_bf16(
                        af, bfr[ks][nt], acc[mt][nt], 0, 0, 0);
            }
        #pragma unroll
        for (int mt = 0; mt < 2; ++mt)
            #pragma unroll
            for (int nt = 0; nt < 4; ++nt)
                #pragma unroll
                for (int i = 0; i < 4; ++i)
                    HA[(mbase + mt * 16 + q * 4 + i) * HD + nt * 16 + l15] =
                        f2bf(acc[mt][nt][i]);
    }
    __syncthreads();

    // ---- SpMM2 + fused epilogue: tv[c] = sum_d relu((S@g)[c,d] + b2[d]) * W3[d]
    #pragma unroll 1
    for (int set = 0; set < 4; ++set) {
        int r  = set * 128 + wave * 8 + grp;
        int e0 = sptr[r], e1 = sptr[r + 1];
        int c  = scm[r];
        float a[8];
        #pragma unroll
        for (int j = 0; j < 8; ++j) a[j] = 0.0f;
        int e = e0;
        for (; e + 2 <= e1; e += 2) {
            int pe0 = eps[e], pe1 = eps[e + 1];
            EDGE_MAC(pe0);
            EDGE_MAC(pe1);
        }
        if (e < e1) { int pe0 = eps[e]; EDGE_MAC(pe0); }
        float v = 0.0f;
        #pragma unroll
        for (int j = 0; j < 8; ++j)
            v += fmaxf(a[j] + b2v[j], 0.0f) * w3v[j];
        v += __shfl_xor(v, 1, 64);
        v += __shfl_xor(v, 2, 64);
        v += __shfl_xor(v, 4, 64);
        if ((lane & 7) == 0) tv[c] = v;
    }
    __syncthreads();

    // ---- SpMM3: slog[c] = (S @ tv)[c] + b3   (one rank per thread)
    if (t < NUM) {
        int e0 = sptr[t], e1 = sptr[t + 1];
        float a = 0.0f;
        for (int e = e0; e < e1; ++e) {
            unsigned pe = (unsigned)eps[e];
            a = fmaf(__uint_as_float(pe << 16), tv[pe >> 16], a);
        }
        slog[scm[t]] = a + b3[0];
    }
    __syncthreads();

    // ---- softmax stats over [0, MAIN)
    if (t < 64) {
        float v = (t < MAIN) ? slog[t] : -1e30f;
        float m = v;
        m = fmaxf(m, __shfl_xor(m, 1, 64));
        m = fmaxf(m, __shfl_xor(m, 2, 64));
        m = fmaxf(m, __shfl_xor(m, 4, 64));
        m = fmaxf(m, __shfl_xor(m, 8, 64));
        float ev = (t < MAIN) ? __expf(v - m) : 0.0f;
        ev += __shfl_xor(ev, 1, 64);
        ev += __shfl_xor(ev, 2, 64);
        ev += __shfl_xor(ev, 4, 64);
        ev += __shfl_xor(ev, 8, 64);
        if (t == 0) { sred[0] = m; sred[1] = ev; }
    }
    __syncthreads();

    if (t < NUM) {
        float l = slog[t];
        float o = (t < MAIN) ? __expf(l - sred[0]) / sred[1]
                             : 1.0f / (1.0f + __expf(-l));
        out[b * NUM + t] = o;
    }
#undef EDGE_MAC
}

// ---------------------------------------------------------------------------
extern "C" void kernel_launch(void* const* d_in, const int* in_sizes, int n_in,
                              void* d_out, int out_size, void* d_ws, size_t ws_size,
                              hipStream_t stream) {
    const float* x    = (const float*)d_in[0];
    const float* emb  = (const float*)d_in[1];
    const float* W1   = (const float*)d_in[2];
    const float* b1   = (const float*)d_in[3];
    const float* W2   = (const float*)d_in[4];
    const float* b2   = (const float*)d_in[5];
    const float* W3   = (const float*)d_in[6];
    const float* b3   = (const float*)d_in[7];
    const int*   erow = (const int*)d_in[8];
    const int*   ecol = (const int*)d_in[9];

    gcn_one<<<NB, 1024, 0, stream>>>(x, emb, W1, W2, b1, b2, W3, b3,
                                     erow, ecol, (float*)d_out);
}

// Round 9
// 157.441 us; speedup vs baseline: 1.2201x; 1.2201x over previous
//
#include <hip/hip_runtime.h>
#include <stdint.h>

#define NB    1024   // batch
#define NUM   512    // nodes
#define HD    64     // hidden dim
#define NE    4096   // edges
#define NEP   4608   // padded edge capacity (each column padded to even count)
#define MAIN  10     // softmax segment
#define HBS   72     // HB row stride (shorts): 144 B, 16B-aligned b128 slots

typedef __attribute__((ext_vector_type(8))) short short8;
typedef __attribute__((ext_vector_type(4))) float f32x4;

__device__ __forceinline__ short f2bf(float f) {
    uint32_t u = __float_as_uint(f);
    u += 0x7fffu + ((u >> 16) & 1u);   // RNE
    return (short)(u >> 16);
}
__device__ __forceinline__ float bf2f(short s) {
    return __uint_as_float(((uint32_t)(uint16_t)s) << 16);
}

// ---------------------------------------------------------------------------
// Prep: block 0 builds degree-sorted, even-padded CSR via wave-shfl scans;
// blocks 1..72 cast E1 = emb@W1 and W2T = W2^T to bf16.
// ---------------------------------------------------------------------------
__global__ __launch_bounds__(512) void prep_all(
    const int* __restrict__ erow, const int* __restrict__ ecol,
    const float* __restrict__ emb, const float* __restrict__ W1,
    const float* __restrict__ W2,
    int* __restrict__ rsptr, int* __restrict__ colmap, int* __restrict__ epk,
    short* __restrict__ E1, short* __restrict__ W2T)
{
    const int t = threadIdx.x;
    if (blockIdx.x != 0) {
        int g = (blockIdx.x - 1) * 512 + t;     // 72 x 512 = 36864
        if (g < NUM * HD) {
            int node = g >> 6, dim = g & 63;
            float acc = 0.0f;
            #pragma unroll
            for (int k = 0; k < HD; ++k) acc += emb[node * HD + k] * W1[k * HD + dim];
            E1[g] = f2bf(acc);
        } else if (g < NUM * HD + HD * HD) {
            int j = g - NUM * HD;
            int dout = j >> 6, din = j & 63;
            W2T[j] = f2bf(W2[din * HD + dout]);
        }
        return;
    }

    __shared__ int   sdeg[NUM];     // degree -> bin cursor -> edge cursor
    __shared__ int   aux[NUM];      // histogram scan -> rank starts
    __shared__ float sdv[NUM];
    __shared__ int   rnk[NUM];
    __shared__ int   rdg[NUM];      // padded degree by rank
    __shared__ int   wsum[8];

    const int lane = t & 63, wv = t >> 6;

    sdeg[t] = 0; aux[t] = 0;
    __syncthreads();
    for (int e = t; e < NE; e += 512) atomicAdd(&sdeg[ecol[e]], 1);
    __syncthreads();
    const int deg  = sdeg[t];
    const int pdeg = (deg + 1) & ~1;            // pad to even
    const int dbin = deg < NUM ? deg : NUM - 1;
    sdv[t] = deg > 0 ? rsqrtf((float)deg) : 0.0f;
    atomicAdd(&aux[dbin], 1);
    __syncthreads();
    // scan histogram (shfl)
    {
        int v = aux[t];
        #pragma unroll
        for (int ofs = 1; ofs < 64; ofs <<= 1) {
            int sh = __shfl_up(v, ofs, 64);
            if (lane >= ofs) v += sh;
        }
        if (lane == 63) wsum[wv] = v;
        __syncthreads();
        if (t == 0) {
            int s = 0;
            #pragma unroll
            for (int w = 0; w < 8; ++w) { int tmp = wsum[w]; wsum[w] = s; s += tmp; }
        }
        __syncthreads();
        int inc = v + wsum[wv];
        sdeg[t] = inc - ((dbin == t) ? 0 : 0);  // placeholder; real cursor below
        aux[t]  = inc;                          // inclusive histogram scan
        __syncthreads();
        sdeg[t] = (t == 0) ? 0 : aux[t - 1];    // bin cursors (exclusive)
        __syncthreads();
    }
    {
        int r = atomicAdd(&sdeg[dbin], 1);      // degree-sorted rank
        rnk[t] = r;
        rdg[r] = pdeg;
        colmap[r] = t;
    }
    __syncthreads();
    // scan padded degrees by rank -> rank CSR (all-even offsets)
    {
        int dv = rdg[t], v = dv;
        #pragma unroll
        for (int ofs = 1; ofs < 64; ofs <<= 1) {
            int sh = __shfl_up(v, ofs, 64);
            if (lane >= ofs) v += sh;
        }
        if (lane == 63) wsum[wv] = v;
        __syncthreads();
        if (t == 0) {
            int s = 0;
            #pragma unroll
            for (int w = 0; w < 8; ++w) { int tmp = wsum[w]; wsum[w] = s; s += tmp; }
        }
        __syncthreads();
        int inc  = v + wsum[wv];
        int excl = inc - dv;
        rsptr[t] = excl;
        if (t == NUM - 1) rsptr[NUM] = inc;
        aux[t] = excl;                          // rank start
        __syncthreads();
    }
    sdeg[t] = aux[rnk[t]];                      // per-ORIGINAL-col edge cursor
    __syncthreads();
    for (int i = t; i < NEP; i += 512) epk[i] = 0;   // zero pads
    __syncthreads();
    for (int e = t; e < NE; e += 512) {
        int c = ecol[e], rr = erow[e];
        int p = atomicAdd(&sdeg[c], 1);
        unsigned nb = (unsigned short)f2bf(sdv[rr] * sdv[c]);
        epk[p] = (rr << 16) | (int)nb;
    }
}

// ---------------------------------------------------------------------------
// Body: one block (1024 thr, 16 waves) per batch element.
// ---------------------------------------------------------------------------
__global__ __launch_bounds__(1024, 4) void gcn_body(
    const float* __restrict__ x, const short* __restrict__ E1,
    const short* __restrict__ W2T,
    const float* __restrict__ b1, const float* __restrict__ b2,
    const float* __restrict__ W3, const float* __restrict__ b3,
    const int* __restrict__ rsptrg, const int* __restrict__ colmap,
    const int* __restrict__ epkg,
    float* __restrict__ out)
{
    __shared__ short HA[NUM * HD];     // 65536 B [node][64] (B1, later g = h1@W2)
    __shared__ short HB[NUM * HBS];    // 73728 B [node][72] (h1); overlays tv/slog
    __shared__ int   eps[NEP];         // 18432 B packed padded edges
    __shared__ int   sptr[513];
    __shared__ float sred[2];

    float* tv   = (float*)HB;          // 512 floats (after MFMA, HB dead)
    float* slog = ((float*)HB) + NUM;

    const int t     = threadIdx.x;
    const int b     = blockIdx.x;
    const int lane  = t & 63;
    const int wave  = t >> 6;          // 0..15
    const int q     = lane >> 4;
    const int l15   = lane & 15;
    const int grp   = lane >> 3;       // column slot within wave
    const int dbase = (lane & 7) * 8;  // this lane's 8-dim strip

    // ---- stage edges + csr
    {
        const int4* g4 = (const int4*)epkg;
        *(int4*)&eps[t * 4] = g4[t];                       // 4096 ints
        if (t < 128) *(int4*)&eps[4096 + t * 4] = g4[1024 + t];
    }
    if (t < 513) sptr[t] = rsptrg[t];

    // ---- build HA = B1: B1[r][d] = x[b,r] * E1[r][d]
    #pragma unroll
    for (int p = 0; p < 4; ++p) {
        int i = t + p * 1024;
        int r = i >> 3, d8 = (i & 7) * 8;
        float xr = x[b * NUM + r];
        short8 e = *(const short8*)&E1[r * HD + d8];
        short8 o;
        #pragma unroll
        for (int j = 0; j < 8; ++j) o[j] = f2bf(xr * bf2f(e[j]));
        *(short8*)&HA[r * HD + d8] = o;
    }

    // per-lane bias/weight strips
    float b1v[8], b2v[8], w3v[8];
    {
        f32x4 u0 = *(const f32x4*)&b1[dbase], u1 = *(const f32x4*)&b1[dbase + 4];
        f32x4 v0 = *(const f32x4*)&b2[dbase], v1 = *(const f32x4*)&b2[dbase + 4];
        f32x4 w0 = *(const f32x4*)&W3[dbase], w1 = *(const f32x4*)&W3[dbase + 4];
        #pragma unroll
        for (int j = 0; j < 4; ++j) {
            b1v[j] = u0[j]; b1v[j + 4] = u1[j];
            b2v[j] = v0[j]; b2v[j + 4] = v1[j];
            w3v[j] = w0[j]; w3v[j + 4] = w1[j];
        }
    }
    __syncthreads();

// odd dims use the packed word directly as f32: low-16 garbage < bf16 ulp.
#define EDGE_MAC(pe)                                                          \
    {                                                                         \
        float n = __uint_as_float((unsigned)(pe) << 16);                      \
        uint4 hv = *(const uint4*)&HA[((unsigned)(pe) >> 16) * HD + dbase];   \
        a[0] = fmaf(n, __uint_as_float(hv.x << 16), a[0]);                    \
        a[1] = fmaf(n, __uint_as_float(hv.x), a[1]);                          \
        a[2] = fmaf(n, __uint_as_float(hv.y << 16), a[2]);                    \
        a[3] = fmaf(n, __uint_as_float(hv.y), a[3]);                          \
        a[4] = fmaf(n, __uint_as_float(hv.z << 16), a[4]);                    \
        a[5] = fmaf(n, __uint_as_float(hv.z), a[5]);                          \
        a[6] = fmaf(n, __uint_as_float(hv.w << 16), a[6]);                    \
        a[7] = fmaf(n, __uint_as_float(hv.w), a[7]);                          \
    }

    // ---- SpMM1: h1 = relu(S @ B1 + b1) -> HB[c][d]
    #pragma unroll 1
    for (int set = 0; set < 4; ++set) {
        int r  = set * 128 + wave * 8 + grp;
        int e0 = sptr[r], e1 = sptr[r + 1];
        int c  = colmap[r];
        float a[8];
        #pragma unroll
        for (int j = 0; j < 8; ++j) a[j] = 0.0f;
        int e = e0;
        for (; e + 4 <= e1; e += 4) {
            int2 pa = *(const int2*)&eps[e];
            int2 pb = *(const int2*)&eps[e + 2];
            EDGE_MAC(pa.x); EDGE_MAC(pa.y); EDGE_MAC(pb.x); EDGE_MAC(pb.y);
        }
        if (e < e1) {
            int2 pa = *(const int2*)&eps[e];
            EDGE_MAC(pa.x); EDGE_MAC(pa.y);
        }
        short8 o;
        #pragma unroll
        for (int j = 0; j < 8; ++j) o[j] = f2bf(fmaxf(a[j] + b1v[j], 0.0f));
        *(short8*)&HB[c * HBS + dbase] = o;
    }
    __syncthreads();

    // ---- MFMA: g = h1 @ W2 -> HA[node][dout]
    {
        short8 bfr[2][4];
        #pragma unroll
        for (int ks = 0; ks < 2; ++ks)
            #pragma unroll
            for (int nt = 0; nt < 4; ++nt)
                bfr[ks][nt] = *(const short8*)&W2T[(nt * 16 + l15) * HD + ks * 32 + q * 8];
        f32x4 acc[2][4];
        #pragma unroll
        for (int mt = 0; mt < 2; ++mt)
            #pragma unroll
            for (int nt = 0; nt < 4; ++nt) acc[mt][nt] = (f32x4){0.f, 0.f, 0.f, 0.f};
        const int mbase = wave * 32;
        #pragma unroll
        for (int mt = 0; mt < 2; ++mt)
            #pragma unroll
            for (int ks = 0; ks < 2; ++ks) {
                short8 af = *(const short8*)&HB[(mbase + mt * 16 + l15) * HBS
                                                + ks * 32 + q * 8];
                #pragma unroll
                for (int nt = 0; nt < 4; ++nt)
                    acc[mt][nt] = __builtin_amdgcn_mfma_f32_16x16x32_bf16(
                        af, bfr[ks][nt], acc[mt][nt], 0, 0, 0);
            }
        #pragma unroll
        for (int mt = 0; mt < 2; ++mt)
            #pragma unroll
            for (int nt = 0; nt < 4; ++nt)
                #pragma unroll
                for (int i = 0; i < 4; ++i)
                    HA[(mbase + mt * 16 + q * 4 + i) * HD + nt * 16 + l15] =
                        f2bf(acc[mt][nt][i]);
    }
    __syncthreads();

    // ---- SpMM2 + fused epilogue: tv[c] = sum_d relu((S@g)[c,d] + b2[d]) * W3[d]
    #pragma unroll 1
    for (int set = 0; set < 4; ++set) {
        int r  = set * 128 + wave * 8 + grp;
        int e0 = sptr[r], e1 = sptr[r + 1];
        int c  = colmap[r];
        float a[8];
        #pragma unroll
        for (int j = 0; j < 8; ++j) a[j] = 0.0f;
        int e = e0;
        for (; e + 4 <= e1; e += 4) {
            int2 pa = *(const int2*)&eps[e];
            int2 pb = *(const int2*)&eps[e + 2];
            EDGE_MAC(pa.x); EDGE_MAC(pa.y); EDGE_MAC(pb.x); EDGE_MAC(pb.y);
        }
        if (e < e1) {
            int2 pa = *(const int2*)&eps[e];
            EDGE_MAC(pa.x); EDGE_MAC(pa.y);
        }
        float v = 0.0f;
        #pragma unroll
        for (int j = 0; j < 8; ++j)
            v += fmaxf(a[j] + b2v[j], 0.0f) * w3v[j];
        v += __shfl_xor(v, 1, 64);
        v += __shfl_xor(v, 2, 64);
        v += __shfl_xor(v, 4, 64);
        if ((lane & 7) == 0) tv[c] = v;
    }
    __syncthreads();

    // ---- SpMM3: slog[col] = (S @ tv)[col] + b3  (one rank per thread)
    if (t < NUM) {
        int e0 = sptr[t], e1 = sptr[t + 1];
        float a = 0.0f;
        for (int e = e0; e < e1; ++e) {
            unsigned pe = (unsigned)eps[e];
            a = fmaf(__uint_as_float(pe << 16), tv[pe >> 16], a);
        }
        slog[colmap[t]] = a + b3[0];
    }
    __syncthreads();

    // ---- softmax stats over [0, MAIN)
    if (t < 64) {
        float v = (t < MAIN) ? slog[t] : -1e30f;
        float m = v;
        m = fmaxf(m, __shfl_xor(m, 1, 64));
        m = fmaxf(m, __shfl_xor(m, 2, 64));
        m = fmaxf(m, __shfl_xor(m, 4, 64));
        m = fmaxf(m, __shfl_xor(m, 8, 64));
        float ev = (t < MAIN) ? __expf(v - m) : 0.0f;
        ev += __shfl_xor(ev, 1, 64);
        ev += __shfl_xor(ev, 2, 64);
        ev += __shfl_xor(ev, 4, 64);
        ev += __shfl_xor(ev, 8, 64);
        if (t == 0) { sred[0] = m; sred[1] = ev; }
    }
    __syncthreads();

    if (t < NUM) {
        float l = slog[t];
        float o = (t < MAIN) ? __expf(l - sred[0]) / sred[1]
                             : 1.0f / (1.0f + __expf(-l));
        out[b * NUM + t] = o;
    }
#undef EDGE_MAC
}

// ---------------------------------------------------------------------------
extern "C" void kernel_launch(void* const* d_in, const int* in_sizes, int n_in,
                              void* d_out, int out_size, void* d_ws, size_t ws_size,
                              hipStream_t stream) {
    const float* x    = (const float*)d_in[0];
    const float* emb  = (const float*)d_in[1];
    const float* W1   = (const float*)d_in[2];
    const float* b1   = (const float*)d_in[3];
    const float* W2   = (const float*)d_in[4];
    const float* b2   = (const float*)d_in[5];
    const float* W3   = (const float*)d_in[6];
    const float* b3   = (const float*)d_in[7];
    const int*   erow = (const int*)d_in[8];
    const int*   ecol = (const int*)d_in[9];

    char* ws = (char*)d_ws;
    int*   rsptr  = (int*)ws;                // 513 ints  [0, 2052)
    int*   colmap = (int*)(ws + 2176);       // 512 ints  [2176, 4224)
    int*   epk    = (int*)(ws + 4224);       // 4608 ints [4224, 22656)
    short* E1     = (short*)(ws + 22656);    // 32768 sh  [22656, 88192)
    short* W2T    = (short*)(ws + 88192);    // 4096 sh   [88192, 96384)

    prep_all<<<73, 512, 0, stream>>>(erow, ecol, emb, W1, W2,
                                     rsptr, colmap, epk, E1, W2T);
    gcn_body<<<NB, 1024, 0, stream>>>(x, E1, W2T, b1, b2, W3, b3,
                                      rsptr, colmap, epk, (float*)d_out);
}